// Round 9
// baseline (24.610 us; speedup 1.0000x reference)
//
#include <hip/hip_runtime.h>

typedef float f32x4 __attribute__((ext_vector_type(4)));
typedef short bf16x8 __attribute__((ext_vector_type(8)));

#define NB   16
#define CIN  32
#define HW   64
#define CKK  288
#define QD   64

// ws layout (ushort elems):
//  weight tensors in MFMA fragment-major order: frag f = [f][lane][8] -> lane reads base+lane*8
#define WS_WSF 0          // GEMM1 B: 36 frags (kk*4+jt)                  -> 18432
#define WS_MCF 18432      // GEMM2 B: 16 frags (kk*8+n), n<4 Re, n>=4 Im  -> 8192
#define WS_WOF 26624      // GEMM3 B: 8 frags (kk*4+ot)                   -> 4096
#define WS_XQF 30720      // x transposed to channel-last bf16 [b][y][x][c] -> 2097152

__device__ __forceinline__ unsigned short f2bf(float f) {
  unsigned u = __builtin_bit_cast(unsigned, f);
  u += 0x7FFFu + ((u >> 16) & 1u);   // RNE
  return (unsigned short)(u >> 16);
}

struct C2 { float r, i; };
struct M2 { C2 a, b, c, d; };  // [[a,b],[c,d]]

__device__ __forceinline__ C2 cmul(C2 x, C2 y) { return { x.r*y.r - x.i*y.i, x.r*y.i + x.i*y.r }; }
__device__ __forceinline__ C2 cadd(C2 x, C2 y) { return { x.r + y.r, x.i + y.i }; }
__device__ __forceinline__ M2 mmul(M2 X, M2 Y) {  // X*Y (Y applied first)
  return { cadd(cmul(X.a, Y.a), cmul(X.b, Y.c)),
           cadd(cmul(X.a, Y.b), cmul(X.b, Y.d)),
           cadd(cmul(X.c, Y.a), cmul(X.d, Y.c)),
           cadd(cmul(X.c, Y.b), cmul(X.d, Y.d)) };
}

__device__ __forceinline__ M2 mRX(float t) {
  float s, c; __sincosf(t * 0.5f, &s, &c);
  return { {c,0.f}, {0.f,-s}, {0.f,-s}, {c,0.f} };
}
__device__ __forceinline__ M2 mRY(float t) {
  float s, c; __sincosf(t * 0.5f, &s, &c);
  return { {c,0.f}, {-s,0.f}, {s,0.f}, {c,0.f} };
}
__device__ __forceinline__ M2 mU3(float t, float p, float lm) {
  float s, c; __sincosf(t * 0.5f, &s, &c);
  float sp, cp; __sincosf(p, &sp, &cp);
  float sl, cl; __sincosf(lm, &sl, &cl);
  float spl, cpl; __sincosf(p + lm, &spl, &cpl);
  return { {c,0.f}, {-cl*s, -sl*s}, {cp*s, sp*s}, {cpl*c, spl*c} };
}

// grid = 1077: [0,1024) x transpose, [1024,1060) WsF, 1060 WoF, [1061,1077) circuit
__global__ __launch_bounds__(256) void prep_kernel(
    const float* __restrict__ x,
    const float* __restrict__ in_proj_w, const float* __restrict__ inp_scale,
    const float* __restrict__ weights, const float* __restrict__ meas_w,
    const float* __restrict__ out_proj_w, unsigned short* __restrict__ ws)
{
  const int tid = threadIdx.x, blk = blockIdx.x;

  if (blk < 1024) {                      // x[b][c][y][x] f32 -> xq[b][y][x][c] bf16
    const int b = blk >> 6, y = blk & 63;
    const int lane = tid & 63, w = tid >> 6;     // w = channel group (8 ch)
    const float* src = x + ((b * CIN + w * 8) * HW + y) * HW + lane;
    unsigned short* dst = ws + WS_XQF + (size_t)((b * HW + y) * HW + lane) * CIN + w * 8;
    bf16x8 o8;
#pragma unroll
    for (int j = 0; j < 8; ++j) o8[j] = (short)f2bf(src[j * HW * HW]);
    *(bf16x8*)dst = o8;
    return;
  }
  const int blk2 = blk - 1024;

  if (blk2 < 36) {                       // WsF: frag f = kk*4+jt, 512 ushorts
    int f = blk2, kk = f >> 2, jt = f & 3;
#pragma unroll
    for (int u = 0; u < 2; ++u) {
      int r = tid * 2 + u;
      int lw = r >> 3, e = r & 7;
      int row = jt * 16 + (lw & 15);
      int ch = (lw >> 4) * 8 + e;
      int src = ch * 9 + kk;
      ws[WS_WSF + f * 512 + r] = f2bf(in_proj_w[row * CKK + src] * inp_scale[src]);
    }
    return;
  }
  if (blk2 == 36) {                      // WoF: 8 frags x 512
#pragma unroll
    for (int m = 0; m < 16; ++m) {
      int d = tid * 16 + m;
      int f = d >> 9, r = d & 511;
      int lw = r >> 3, e = r & 7;
      int kk = f >> 2, ot = f & 3;
      int src = (ot * 16 + (lw & 15)) * 64 + kk * 32 + (lw >> 4) * 8 + e;
      ws[WS_WOF + d] = f2bf(out_proj_w[src]);
    }
    return;
  }

  // ======== circuit: one column per wave (validated R7) ========
  const int lane = tid & 63, wid = tid >> 6;
  const int col = (blk2 - 37) * 4 + wid;         // 0..63, wave-uniform

  float re, im;
  {
    C2 amp = {1.f, 0.f};
#pragma unroll
    for (int q = 0; q < 6; ++q) {
      M2 G = mmul(mRY(weights[q * 3 + 1]), mRX(weights[q * 3 + 0]));
      int rb = (lane >> (5 - q)) & 1;
      int cb = (col >> (5 - q)) & 1;
      C2 sel = rb ? (cb ? G.d : G.c) : (cb ? G.b : G.a);
      amp = cmul(amp, sel);
    }
    re = amp.r; im = amp.i;
  }

  const int t1 = (lane ^ (lane >> 1) ^ (lane >> 2) ^ (lane >> 3) ^ (lane >> 4) ^ (lane >> 5)) & 63;
  const int t2 = (lane ^ (lane >> 2) ^ (lane >> 4)) & 63;

  auto applyM = [&](int maskShuf, int rb, M2 U) {
    float arr = rb ? U.d.r : U.a.r, ari = rb ? U.d.i : U.a.i;
    float brr = rb ? U.c.r : U.b.r, bri = rb ? U.c.i : U.b.i;
    float pre = __shfl_xor(re, maskShuf);
    float pim = __shfl_xor(im, maskShuf);
    float nr = arr * re - ari * im + brr * pre - bri * pim;
    float ni = arr * im + ari * re + brr * pim + bri * pre;
    re = nr; im = ni;
  };

  const int MK1[6] = {0x01, 0x03, 0x06, 0x0C, 0x18, 0x30};  // sigma1^-1(e_b)
  const int MK2[6] = {0x01, 0x02, 0x05, 0x0A, 0x14, 0x28};  // sigma2^-1(e_b)

#pragma unroll
  for (int q = 0; q < 6; ++q) {
    const int b = 5 - q;
    M2 U = mmul(mmul(mRY(weights[18 + q * 3 + 1]), mRX(weights[18 + q * 3 + 0])),
                mRY(weights[q * 3 + 2]));           // merged: l0-trailing-RY, l1 RX, l1 RY
    applyM(MK1[b], (t1 >> b) & 1, U);
  }
#pragma unroll
  for (int q = 0; q < 6; ++q) {
    const int b = 5 - q;
    M2 U = mmul(mU3(meas_w[q * 3], meas_w[q * 3 + 1], meas_w[q * 3 + 2]),
                mRY(weights[18 + q * 3 + 2]));      // merged: l1-trailing-RY, meas U3
    applyM(MK2[b], (t2 >> b) & 1, U);
  }

  unsigned short* McF = ws + WS_MCF;
  const int nRe = t2 >> 4, c16r = t2 & 15;
  const int kk = col >> 5, gc = (col >> 3) & 3, e = col & 7;
  const int off = (gc * 16 + c16r) * 8 + e;
  McF[(kk * 8 + nRe) * 512 + off]     = f2bf(re);
  McF[(kk * 8 + 4 + nRe) * 512 + off] = f2bf(im);
}

#define LDA 72
#define LDO 65

__global__ __launch_bounds__(256) void main_kernel(
    const float* __restrict__ b_in, const float* __restrict__ b_out,
    const unsigned short* __restrict__ ws, float* __restrict__ out)
{
  __shared__ __align__(16) unsigned char smem[18432];
  unsigned short* a_lds = (unsigned short*)smem;
  unsigned short* p_lds = (unsigned short*)(smem + 9216);
  float* o_lds = (float*)smem;

  const int tid = threadIdx.x, lane = tid & 63, wid = tid >> 6;
  const int g = lane >> 4, c16 = lane & 15;
  // XCD-chunked swizzle (1024 % 8 == 0 -> bijective)
  const int blk = (blockIdx.x & 7) * 128 + (blockIdx.x >> 3);
  const int b = blk >> 6, h = blk & 63;

  const unsigned short* WsF = ws + WS_WSF;
  const unsigned short* McF = ws + WS_MCF;
  const unsigned short* WoF = ws + WS_WOF;
  const unsigned short* xqb = ws + WS_XQF + (size_t)b * (HW * HW * CIN);

  // ---- GEMM1: xq[64 pix][64] = patch(64x288) * Ws^T + b_in ----
  f32x4 acc[4];
#pragma unroll
  for (int jt = 0; jt < 4; ++jt) { float bi = b_in[jt * 16 + c16]; acc[jt] = f32x4{bi, bi, bi, bi}; }

  const int ar = wid * 16 + c16;             // this lane's pixel w
  const int xw0 = (ar >= 1) ? ar - 1 : 0;    // dj=0 clamped
  const int xw2 = (ar <= 62) ? ar + 1 : 63;  // dj=2 clamped
  const bool ok0 = (ar >= 1), ok2 = (ar <= 62);

#pragma unroll
  for (int kk = 0; kk < 9; ++kk) {
    const int di = kk / 3, dj = kk % 3;
    const int y = h + di - 1;                // wave-uniform
    bf16x8 af;
    if ((unsigned)y < 64u) {                 // uniform scalar branch
      const int xwc = (dj == 0) ? xw0 : (dj == 1) ? ar : xw2;
      // one 16B load: 8 channels, channel-last layout
      af = *(const bf16x8*)(xqb + (y * 64 + xwc) * CIN + g * 8);
      const bool okx = (dj == 0) ? ok0 : (dj == 1) ? true : ok2;
      if (!okx)
#pragma unroll
        for (int i = 0; i < 8; ++i) af[i] = 0;
    } else {
#pragma unroll
      for (int i = 0; i < 8; ++i) af[i] = 0;
    }
#pragma unroll
    for (int jt = 0; jt < 4; ++jt) {
      bf16x8 bf_ = *(const bf16x8*)(WsF + (kk * 4 + jt) * 512 + lane * 8);
      acc[jt] = __builtin_amdgcn_mfma_f32_16x16x32_bf16(af, bf_, acc[jt], 0, 0, 0);
    }
  }

  // ---- row norm (C layout: col=lane&15, row=(lane>>4)*4+reg) ----
  float s[4];
#pragma unroll
  for (int r = 0; r < 4; ++r) {
    float t = acc[0][r] * acc[0][r] + acc[1][r] * acc[1][r] +
              acc[2][r] * acc[2][r] + acc[3][r] * acc[3][r];
    t += __shfl_xor(t, 1); t += __shfl_xor(t, 2); t += __shfl_xor(t, 4); t += __shfl_xor(t, 8);
    s[r] = 1.f / (sqrtf(t) + 1e-9f);
  }
  // a_lds rows [wid*16, wid*16+16) are wave-private: no block barrier needed
#pragma unroll
  for (int jt = 0; jt < 4; ++jt)
#pragma unroll
    for (int r = 0; r < 4; ++r)
      a_lds[(wid * 16 + g * 4 + r) * LDA + jt * 16 + c16] = f2bf(acc[jt][r] * s[r]);

  // ---- circuit GEMM: [u|v](64x128) = a(64x64) * M^T (fragment-major B) ----
  f32x4 uv[8];
#pragma unroll
  for (int n = 0; n < 8; ++n) uv[n] = f32x4{0.f, 0.f, 0.f, 0.f};
#pragma unroll
  for (int kk = 0; kk < 2; ++kk) {
    bf16x8 af = *(const bf16x8*)(a_lds + (wid * 16 + c16) * LDA + kk * 32 + g * 8);
#pragma unroll
    for (int n = 0; n < 8; ++n) {
      bf16x8 bf_ = *(const bf16x8*)(McF + (kk * 8 + n) * 512 + lane * 8);
      uv[n] = __builtin_amdgcn_mfma_f32_16x16x32_bf16(af, bf_, uv[n], 0, 0, 0);
    }
  }

  // ---- probs = u^2 + v^2 (p_lds rows also wave-private) ----
#pragma unroll
  for (int n = 0; n < 4; ++n)
#pragma unroll
    for (int r = 0; r < 4; ++r) {
      float p = uv[n][r] * uv[n][r] + uv[n + 4][r] * uv[n + 4][r];
      p_lds[(wid * 16 + g * 4 + r) * LDA + n * 16 + c16] = f2bf(p);
    }

  // ---- out(64x64) = probs * Wout^T + b_out ----
  f32x4 o[4];
#pragma unroll
  for (int ot = 0; ot < 4; ++ot) { float bo = b_out[ot * 16 + c16]; o[ot] = f32x4{bo, bo, bo, bo}; }
#pragma unroll
  for (int kk = 0; kk < 2; ++kk) {
    bf16x8 af = *(const bf16x8*)(p_lds + (wid * 16 + c16) * LDA + kk * 32 + g * 8);
#pragma unroll
    for (int ot = 0; ot < 4; ++ot) {
      bf16x8 bf_ = *(const bf16x8*)(WoF + (kk * 4 + ot) * 512 + lane * 8);
      o[ot] = __builtin_amdgcn_mfma_f32_16x16x32_bf16(af, bf_, o[ot], 0, 0, 0);
    }
  }

  __syncthreads();   // all waves done reading a_lds/p_lds before o_lds overwrites
#pragma unroll
  for (int ot = 0; ot < 4; ++ot)
#pragma unroll
    for (int r = 0; r < 4; ++r)
      o_lds[(ot * 16 + c16) * LDO + wid * 16 + g * 4 + r] = o[ot][r];
  __syncthreads();

  float* outb = out + (size_t)b * QD * HW * HW + h * HW;
#pragma unroll
  for (int it = 0; it < 16; ++it) {
    int orow = it * 4 + wid;
    outb[orow * (HW * HW) + lane] = o_lds[orow * LDO + lane];
  }
}

extern "C" void kernel_launch(void* const* d_in, const int* in_sizes, int n_in,
                              void* d_out, int out_size, void* d_ws, size_t ws_size,
                              hipStream_t stream) {
  const float* x          = (const float*)d_in[0];
  const float* inp_scale  = (const float*)d_in[1];
  const float* in_proj_w  = (const float*)d_in[2];
  const float* in_proj_b  = (const float*)d_in[3];
  const float* weights    = (const float*)d_in[4];
  const float* meas_w     = (const float*)d_in[5];
  const float* out_proj_w = (const float*)d_in[6];
  const float* out_proj_b = (const float*)d_in[7];
  unsigned short* ws = (unsigned short*)d_ws;

  prep_kernel<<<1077, 256, 0, stream>>>(x, in_proj_w, inp_scale, weights, meas_w, out_proj_w, ws);
  main_kernel<<<NB * HW, 256, 0, stream>>>(in_proj_b, out_proj_b, ws, (float*)d_out);
}

// Round 10
// 22.323 us; speedup vs baseline: 1.1024x; 1.1024x over previous
//
#include <hip/hip_runtime.h>

typedef float f32x4 __attribute__((ext_vector_type(4)));
typedef short bf16x8 __attribute__((ext_vector_type(8)));

#define NB   16
#define CIN  32
#define HW   64
#define CKK  288
#define QD   64

// ws layout (ushort elems):
//  weight tensors in MFMA fragment-major order: frag f = [f][lane][8] -> lane reads base+lane*8
//  [0, 30720) is ONE contiguous weight region staged to LDS by main blocks.
#define WS_WSF 0          // GEMM1 B: 36 frags (kk*4+jt)                  -> 18432
#define WS_MCF 18432      // GEMM2 B: 16 frags (kk*8+n), n<4 Re, n>=4 Im  -> 8192
#define WS_WOF 26624      // GEMM3 B: 8 frags (kk*4+ot)                   -> 4096
#define WS_WEND 30720     // end of weight region (61440 bytes)
#define WS_XQF 30720      // x transposed to channel-last bf16 [b][y][x][c]

__device__ __forceinline__ unsigned short f2bf(float f) {
  unsigned u = __builtin_bit_cast(unsigned, f);
  u += 0x7FFFu + ((u >> 16) & 1u);   // RNE
  return (unsigned short)(u >> 16);
}

struct C2 { float r, i; };
struct M2 { C2 a, b, c, d; };  // [[a,b],[c,d]]

__device__ __forceinline__ C2 cmul(C2 x, C2 y) { return { x.r*y.r - x.i*y.i, x.r*y.i + x.i*y.r }; }
__device__ __forceinline__ C2 cadd(C2 x, C2 y) { return { x.r + y.r, x.i + y.i }; }
__device__ __forceinline__ M2 mmul(M2 X, M2 Y) {  // X*Y (Y applied first)
  return { cadd(cmul(X.a, Y.a), cmul(X.b, Y.c)),
           cadd(cmul(X.a, Y.b), cmul(X.b, Y.d)),
           cadd(cmul(X.c, Y.a), cmul(X.d, Y.c)),
           cadd(cmul(X.c, Y.b), cmul(X.d, Y.d)) };
}

__device__ __forceinline__ M2 mRX(float t) {
  float s, c; __sincosf(t * 0.5f, &s, &c);
  return { {c,0.f}, {0.f,-s}, {0.f,-s}, {c,0.f} };
}
__device__ __forceinline__ M2 mRY(float t) {
  float s, c; __sincosf(t * 0.5f, &s, &c);
  return { {c,0.f}, {-s,0.f}, {s,0.f}, {c,0.f} };
}
__device__ __forceinline__ M2 mU3(float t, float p, float lm) {
  float s, c; __sincosf(t * 0.5f, &s, &c);
  float sp, cp; __sincosf(p, &sp, &cp);
  float sl, cl; __sincosf(lm, &sl, &cl);
  float spl, cpl; __sincosf(p + lm, &spl, &cpl);
  return { {c,0.f}, {-cl*s, -sl*s}, {cp*s, sp*s}, {cpl*c, spl*c} };
}

// grid = 1077: [0,1024) x transpose, [1024,1060) WsF, 1060 WoF, [1061,1077) circuit
__global__ __launch_bounds__(256) void prep_kernel(
    const float* __restrict__ x,
    const float* __restrict__ in_proj_w, const float* __restrict__ inp_scale,
    const float* __restrict__ weights, const float* __restrict__ meas_w,
    const float* __restrict__ out_proj_w, unsigned short* __restrict__ ws)
{
  const int tid = threadIdx.x, blk = blockIdx.x;

  if (blk < 1024) {                      // x[b][c][y][x] f32 -> xq[b][y][x][c] bf16
    const int b = blk >> 6, y = blk & 63;
    const int lane = tid & 63, w = tid >> 6;     // w = channel group (8 ch)
    const float* src = x + ((b * CIN + w * 8) * HW + y) * HW + lane;
    unsigned short* dst = ws + WS_XQF + (size_t)((b * HW + y) * HW + lane) * CIN + w * 8;
    bf16x8 o8;
#pragma unroll
    for (int j = 0; j < 8; ++j) o8[j] = (short)f2bf(src[j * HW * HW]);
    *(bf16x8*)dst = o8;
    return;
  }
  const int blk2 = blk - 1024;

  if (blk2 < 36) {                       // WsF: frag f = kk*4+jt, 512 ushorts
    int f = blk2, kk = f >> 2, jt = f & 3;
#pragma unroll
    for (int u = 0; u < 2; ++u) {
      int r = tid * 2 + u;
      int lw = r >> 3, e = r & 7;
      int row = jt * 16 + (lw & 15);
      int ch = (lw >> 4) * 8 + e;
      int src = ch * 9 + kk;
      ws[WS_WSF + f * 512 + r] = f2bf(in_proj_w[row * CKK + src] * inp_scale[src]);
    }
    return;
  }
  if (blk2 == 36) {                      // WoF: 8 frags x 512
#pragma unroll
    for (int m = 0; m < 16; ++m) {
      int d = tid * 16 + m;
      int f = d >> 9, r = d & 511;
      int lw = r >> 3, e = r & 7;
      int kk = f >> 2, ot = f & 3;
      int src = (ot * 16 + (lw & 15)) * 64 + kk * 32 + (lw >> 4) * 8 + e;
      ws[WS_WOF + d] = f2bf(out_proj_w[src]);
    }
    return;
  }

  // ======== circuit: one column per wave (validated R7) ========
  const int lane = tid & 63, wid = tid >> 6;
  const int col = (blk2 - 37) * 4 + wid;         // 0..63, wave-uniform

  float re, im;
  {
    C2 amp = {1.f, 0.f};
#pragma unroll
    for (int q = 0; q < 6; ++q) {
      M2 G = mmul(mRY(weights[q * 3 + 1]), mRX(weights[q * 3 + 0]));
      int rb = (lane >> (5 - q)) & 1;
      int cb = (col >> (5 - q)) & 1;
      C2 sel = rb ? (cb ? G.d : G.c) : (cb ? G.b : G.a);
      amp = cmul(amp, sel);
    }
    re = amp.r; im = amp.i;
  }

  const int t1 = (lane ^ (lane >> 1) ^ (lane >> 2) ^ (lane >> 3) ^ (lane >> 4) ^ (lane >> 5)) & 63;
  const int t2 = (lane ^ (lane >> 2) ^ (lane >> 4)) & 63;

  auto applyM = [&](int maskShuf, int rb, M2 U) {
    float arr = rb ? U.d.r : U.a.r, ari = rb ? U.d.i : U.a.i;
    float brr = rb ? U.c.r : U.b.r, bri = rb ? U.c.i : U.b.i;
    float pre = __shfl_xor(re, maskShuf);
    float pim = __shfl_xor(im, maskShuf);
    float nr = arr * re - ari * im + brr * pre - bri * pim;
    float ni = arr * im + ari * re + brr * pim + bri * pre;
    re = nr; im = ni;
  };

  const int MK1[6] = {0x01, 0x03, 0x06, 0x0C, 0x18, 0x30};  // sigma1^-1(e_b)
  const int MK2[6] = {0x01, 0x02, 0x05, 0x0A, 0x14, 0x28};  // sigma2^-1(e_b)

#pragma unroll
  for (int q = 0; q < 6; ++q) {
    const int b = 5 - q;
    M2 U = mmul(mmul(mRY(weights[18 + q * 3 + 1]), mRX(weights[18 + q * 3 + 0])),
                mRY(weights[q * 3 + 2]));           // merged: l0-trailing-RY, l1 RX, l1 RY
    applyM(MK1[b], (t1 >> b) & 1, U);
  }
#pragma unroll
  for (int q = 0; q < 6; ++q) {
    const int b = 5 - q;
    M2 U = mmul(mU3(meas_w[q * 3], meas_w[q * 3 + 1], meas_w[q * 3 + 2]),
                mRY(weights[18 + q * 3 + 2]));      // merged: l1-trailing-RY, meas U3
    applyM(MK2[b], (t2 >> b) & 1, U);
  }

  unsigned short* McF = ws + WS_MCF;
  const int nRe = t2 >> 4, c16r = t2 & 15;
  const int kk = col >> 5, gc = (col >> 3) & 3, e = col & 7;
  const int off = (gc * 16 + c16r) * 8 + e;
  McF[(kk * 8 + nRe) * 512 + off]     = f2bf(re);
  McF[(kk * 8 + 4 + nRe) * 512 + off] = f2bf(im);
}

#define LDA 72    // ushorts per a_lds row
#define LDO 65    // floats per o_lds row

// 512 threads (8 waves), 512 blocks; each block = (batch b, rows h0, h0+1).
// Weights (60KB) staged to LDS once per block; B-reads become ds_read_b128.
__global__ __launch_bounds__(512, 4) void main_kernel(
    const float* __restrict__ b_in, const float* __restrict__ b_out,
    const unsigned short* __restrict__ ws, float* __restrict__ out)
{
  __shared__ __align__(16) unsigned char smem[79872];   // 61440 wts + 18432 a_lds
  unsigned short* w_lds = (unsigned short*)smem;                 // [0, 30720) ush
  unsigned short* a_lds = (unsigned short*)(smem + 61440);       // 128 rows x LDA
  float* o_lds = (float*)smem;                                   // aliases w_lds after barrier

  const int tid = threadIdx.x, lane = tid & 63, wid = tid >> 6;
  const int g = lane >> 4, c16 = lane & 15;
  // XCD-chunked swizzle (512 % 8 == 0 -> bijective)
  const int blk = ((int)blockIdx.x & 7) * 64 + ((int)blockIdx.x >> 3);
  const int b = blk >> 5, h0 = (blk & 31) * 2;
  const int hloc = wid >> 2;                    // which of the 2 rows this wave does
  const int h = h0 + hloc;

  // ---- stage weights global -> LDS (contiguous 30720 ushorts) ----
  for (int c = tid; c < 3840; c += 512) {
    bf16x8 v = *(const bf16x8*)(ws + c * 8);
    *(bf16x8*)(w_lds + c * 8) = v;
  }
  __syncthreads();

  const unsigned short* WsL = w_lds + WS_WSF;
  const unsigned short* McL = w_lds + WS_MCF;
  const unsigned short* WoL = w_lds + WS_WOF;
  const unsigned short* xqb = ws + WS_XQF + (size_t)b * (HW * HW * CIN);

  // ---- GEMM1: xq[128 pix][64] = patch(128x288) * Ws^T + b_in ----
  f32x4 acc[4];
#pragma unroll
  for (int jt = 0; jt < 4; ++jt) { float bi = b_in[jt * 16 + c16]; acc[jt] = f32x4{bi, bi, bi, bi}; }

  const int ar = (wid & 3) * 16 + c16;       // this lane's pixel w
  const int xw0 = (ar >= 1) ? ar - 1 : 0;    // dj=0 clamped
  const int xw2 = (ar <= 62) ? ar + 1 : 63;  // dj=2 clamped
  const bool ok0 = (ar >= 1), ok2 = (ar <= 62);

#pragma unroll
  for (int kk = 0; kk < 9; ++kk) {
    const int di = kk / 3, dj = kk % 3;
    const int y = h + di - 1;                // wave-uniform
    bf16x8 af;
    if ((unsigned)y < 64u) {                 // uniform scalar branch
      const int xwc = (dj == 0) ? xw0 : (dj == 1) ? ar : xw2;
      af = *(const bf16x8*)(xqb + (y * 64 + xwc) * CIN + g * 8);
      const bool okx = (dj == 0) ? ok0 : (dj == 1) ? true : ok2;
      if (!okx)
#pragma unroll
        for (int i = 0; i < 8; ++i) af[i] = 0;
    } else {
#pragma unroll
      for (int i = 0; i < 8; ++i) af[i] = 0;
    }
#pragma unroll
    for (int jt = 0; jt < 4; ++jt) {
      bf16x8 bf_ = *(const bf16x8*)(WsL + (kk * 4 + jt) * 512 + lane * 8);
      acc[jt] = __builtin_amdgcn_mfma_f32_16x16x32_bf16(af, bf_, acc[jt], 0, 0, 0);
    }
  }

  // ---- row norm (C layout: col=lane&15, row=(lane>>4)*4+reg) ----
  float s[4];
#pragma unroll
  for (int r = 0; r < 4; ++r) {
    float t = acc[0][r] * acc[0][r] + acc[1][r] * acc[1][r] +
              acc[2][r] * acc[2][r] + acc[3][r] * acc[3][r];
    t += __shfl_xor(t, 1); t += __shfl_xor(t, 2); t += __shfl_xor(t, 4); t += __shfl_xor(t, 8);
    s[r] = 1.f / (sqrtf(t) + 1e-9f);
  }
  // a_lds rows [wid*16, wid*16+16) are wave-private: no block barrier needed
#pragma unroll
  for (int jt = 0; jt < 4; ++jt)
#pragma unroll
    for (int r = 0; r < 4; ++r)
      a_lds[(wid * 16 + g * 4 + r) * LDA + jt * 16 + c16] = f2bf(acc[jt][r] * s[r]);

  // ---- circuit GEMM: [u|v](128x128) = a(128x64) * M^T ----
  f32x4 uv[8];
#pragma unroll
  for (int n = 0; n < 8; ++n) uv[n] = f32x4{0.f, 0.f, 0.f, 0.f};
#pragma unroll
  for (int kk = 0; kk < 2; ++kk) {
    bf16x8 af = *(const bf16x8*)(a_lds + (wid * 16 + c16) * LDA + kk * 32 + g * 8);
#pragma unroll
    for (int n = 0; n < 8; ++n) {
      bf16x8 bf_ = *(const bf16x8*)(McL + (kk * 8 + n) * 512 + lane * 8);
      uv[n] = __builtin_amdgcn_mfma_f32_16x16x32_bf16(af, bf_, uv[n], 0, 0, 0);
    }
  }

  // ---- probs = u^2 + v^2 (aliases a_lds; rows wave-private, program order safe) ----
#pragma unroll
  for (int n = 0; n < 4; ++n)
#pragma unroll
    for (int r = 0; r < 4; ++r) {
      float p = uv[n][r] * uv[n][r] + uv[n + 4][r] * uv[n + 4][r];
      a_lds[(wid * 16 + g * 4 + r) * LDA + n * 16 + c16] = f2bf(p);
    }

  // ---- out(128x64) = probs * Wout^T + b_out ----
  f32x4 o[4];
#pragma unroll
  for (int ot = 0; ot < 4; ++ot) { float bo = b_out[ot * 16 + c16]; o[ot] = f32x4{bo, bo, bo, bo}; }
#pragma unroll
  for (int kk = 0; kk < 2; ++kk) {
    bf16x8 af = *(const bf16x8*)(a_lds + (wid * 16 + c16) * LDA + kk * 32 + g * 8);
#pragma unroll
    for (int ot = 0; ot < 4; ++ot) {
      bf16x8 bf_ = *(const bf16x8*)(WoL + (kk * 4 + ot) * 512 + lane * 8);
      o[ot] = __builtin_amdgcn_mfma_f32_16x16x32_bf16(af, bf_, o[ot], 0, 0, 0);
    }
  }

  __syncthreads();   // all waves done with w_lds before o_lds overwrites it
#pragma unroll
  for (int ot = 0; ot < 4; ++ot)
#pragma unroll
    for (int r = 0; r < 4; ++r)
      o_lds[hloc * (QD * LDO) + (ot * 16 + c16) * LDO + (wid & 3) * 16 + g * 4 + r] = o[ot][r];
  __syncthreads();

  // coalesced stores: out[b][orow][h0+hl][w]
  float* outb = out + (size_t)b * QD * HW * HW + h0 * HW;
#pragma unroll
  for (int it = 0; it < 16; ++it) {
    int r2 = it * 8 + wid;                 // 0..127
    int orow = r2 >> 1, hl = r2 & 1;
    outb[orow * (HW * HW) + hl * HW + lane] = o_lds[hl * (QD * LDO) + orow * LDO + lane];
  }
}

extern "C" void kernel_launch(void* const* d_in, const int* in_sizes, int n_in,
                              void* d_out, int out_size, void* d_ws, size_t ws_size,
                              hipStream_t stream) {
  const float* x          = (const float*)d_in[0];
  const float* inp_scale  = (const float*)d_in[1];
  const float* in_proj_w  = (const float*)d_in[2];
  const float* in_proj_b  = (const float*)d_in[3];
  const float* weights    = (const float*)d_in[4];
  const float* meas_w     = (const float*)d_in[5];
  const float* out_proj_w = (const float*)d_in[6];
  const float* out_proj_b = (const float*)d_in[7];
  unsigned short* ws = (unsigned short*)d_ws;

  prep_kernel<<<1077, 256, 0, stream>>>(x, in_proj_w, inp_scale, weights, meas_w, out_proj_w, ws);
  main_kernel<<<512, 512, 0, stream>>>(in_proj_b, out_proj_b, ws, (float*)d_out);
}